// Round 1
// baseline (368.568 us; speedup 1.0000x reference)
//
#include <hip/hip_runtime.h>

#define BATCH 512
#define HD    1023
#define K0    2048   // input dim (= K for both big GEMMs)
#define N0    2048   // layer0 out
#define N1    1024   // layer1 out
#define N2    512    // layer2 out (per-cell)
#define NCELL 32

// ---------------- gather: build x[b][0:2048] ----------------
__global__ __launch_bounds__(256) void k_gather(
    const int* __restrict__ pairs, const float* __restrict__ attrs,
    const float* __restrict__ h_drug, float* __restrict__ x) {
  int b = blockIdx.x;
  int p0 = pairs[2 * b], p1 = pairs[2 * b + 1];
  const float* h0 = h_drug + (size_t)p0 * HD;
  const float* h1 = h_drug + (size_t)p1 * HD;
  float* xb = x + (size_t)b * K0;
  for (int i = threadIdx.x; i < HD; i += 256) xb[i] = h0[i];
  for (int i = threadIdx.x; i < HD; i += 256) xb[1024 + i] = h1[i];
  if (threadIdx.x == 0) {
    xb[1023] = attrs[4 * b + 1];
    xb[2047] = attrs[4 * b + 3];
  }
}

// ---------------- fp32 GEMM: Y = relu(X[MxK] * W[NxK]^T + bias) ----------------
#define BM 64
#define BN 64
#define BK 32
#define PAD 4  // keep rows 16B-aligned for float4 LDS reads

__global__ __launch_bounds__(256) void k_gemm_relu(
    const float* __restrict__ X, const float* __restrict__ W,
    const float* __restrict__ bias, float* __restrict__ Y, int N, int K) {
  __shared__ float Xs[BK][BM + PAD];
  __shared__ float Ws[BK][BN + PAD];
  const int bm = blockIdx.y, bn = blockIdx.x;
  const int tid = threadIdx.x;
  const int tx = tid & 15, ty = tid >> 4;  // 16x16 threads, 4x4 acc each

  float acc[4][4] = {};
  const float* Xblk = X + (size_t)(bm * BM) * K;
  const float* Wblk = W + (size_t)(bn * BN) * K;

  const int r0 = tid >> 3;        // 0..31 (rows r0, r0+32)
  const int cq = tid & 7;         // float4 index within BK cols

  for (int ko = 0; ko < K; ko += BK) {
#pragma unroll
    for (int rr = r0; rr < BM; rr += 32) {
      float4 v = *(const float4*)(Xblk + (size_t)rr * K + ko + cq * 4);
      Xs[cq * 4 + 0][rr] = v.x; Xs[cq * 4 + 1][rr] = v.y;
      Xs[cq * 4 + 2][rr] = v.z; Xs[cq * 4 + 3][rr] = v.w;
      float4 w = *(const float4*)(Wblk + (size_t)rr * K + ko + cq * 4);
      Ws[cq * 4 + 0][rr] = w.x; Ws[cq * 4 + 1][rr] = w.y;
      Ws[cq * 4 + 2][rr] = w.z; Ws[cq * 4 + 3][rr] = w.w;
    }
    __syncthreads();
#pragma unroll
    for (int kk = 0; kk < BK; ++kk) {
      float4 a4 = *(const float4*)&Xs[kk][ty * 4];
      float4 b4 = *(const float4*)&Ws[kk][tx * 4];
      float a_[4] = {a4.x, a4.y, a4.z, a4.w};
      float b_[4] = {b4.x, b4.y, b4.z, b4.w};
#pragma unroll
      for (int i = 0; i < 4; ++i)
#pragma unroll
        for (int j = 0; j < 4; ++j) acc[i][j] += a_[i] * b_[j];
    }
    __syncthreads();
  }

#pragma unroll
  for (int i = 0; i < 4; ++i) {
    int row = bm * BM + ty * 4 + i;
#pragma unroll
    for (int j = 0; j < 4; ++j) {
      int col = bn * BN + tx * 4 + j;
      float v = acc[i][j] + bias[col];
      Y[(size_t)row * N + col] = v > 0.f ? v : 0.f;
    }
  }
}

// ---------------- fused head: per-sample L0[c]*y2 -> relu -> dot L1[c] ----------------
__global__ __launch_bounds__(256) void k_head(
    const int* __restrict__ cell, const float* __restrict__ y2,
    const float* __restrict__ L0, const float* __restrict__ O0,
    const float* __restrict__ L1, const float* __restrict__ O1,
    float* __restrict__ out) {
  __shared__ float xs[N1];
  __shared__ float wsum[4];
  const int b = blockIdx.x;
  const int c = cell[b];
  const float* y2b = y2 + (size_t)b * N1;
  for (int i = threadIdx.x; i < N1; i += 256) xs[i] = y2b[i];
  __syncthreads();

  const int wave = threadIdx.x >> 6, lane = threadIdx.x & 63;
  const float* L0c = L0 + (size_t)c * N2 * N1;
  const float* O0c = O0 + (size_t)c * N2;
  const float* L1c = L1 + (size_t)c * N2;

  float partial = 0.f;
  for (int r = wave; r < N2; r += 4) {
    const float* row = L0c + (size_t)r * N1;
    float acc = 0.f;
#pragma unroll
    for (int i = 0; i < N1 / 64; ++i) acc += row[lane + i * 64] * xs[lane + i * 64];
#pragma unroll
    for (int off = 32; off > 0; off >>= 1) acc += __shfl_down(acc, off, 64);
    if (lane == 0) {
      float y3 = acc + O0c[r];
      y3 = y3 > 0.f ? y3 : 0.f;
      partial += y3 * L1c[r];
    }
  }
  if (lane == 0) wsum[wave] = partial;
  __syncthreads();
  if (threadIdx.x == 0) out[b] = wsum[0] + wsum[1] + wsum[2] + wsum[3] + O1[c];
}

// ---------------- launch ----------------
extern "C" void kernel_launch(void* const* d_in, const int* in_sizes, int n_in,
                              void* d_out, int out_size, void* d_ws, size_t ws_size,
                              hipStream_t stream) {
  const int*   pairs  = (const int*)d_in[0];
  const int*   cells  = (const int*)d_in[1];
  const float* attrs  = (const float*)d_in[2];
  const float* h_drug = (const float*)d_in[3];
  const float* W0     = (const float*)d_in[4];
  const float* b0     = (const float*)d_in[5];
  const float* W1     = (const float*)d_in[6];
  const float* b1     = (const float*)d_in[7];
  const float* L0     = (const float*)d_in[8];
  const float* O0     = (const float*)d_in[9];
  const float* L1     = (const float*)d_in[10];
  const float* O1     = (const float*)d_in[11];
  float* out = (float*)d_out;

  float* x  = (float*)d_ws;                 // 512*2048
  float* y1 = x + (size_t)BATCH * K0;       // 512*2048
  float* y2 = y1 + (size_t)BATCH * N0;      // 512*1024

  k_gather<<<BATCH, 256, 0, stream>>>(pairs, attrs, h_drug, x);
  k_gemm_relu<<<dim3(N0 / BN, BATCH / BM), 256, 0, stream>>>(x, W0, b0, y1, N0, K0);
  k_gemm_relu<<<dim3(N1 / BN, BATCH / BM), 256, 0, stream>>>(y1, W1, b1, y2, N1, K0);
  k_head<<<BATCH, 256, 0, stream>>>(cells, y2, L0, O0, L1, O1, out);
}

// Round 2
// 72.135 us; speedup vs baseline: 5.1094x; 5.1094x over previous
//
#include <hip/hip_runtime.h>

typedef short s16x8 __attribute__((ext_vector_type(8)));
typedef float f32x4 __attribute__((ext_vector_type(4)));
typedef unsigned short u16;

#define BATCH 512
#define HD    1023
#define K0    2048
#define N0    2048
#define N1    1024
#define N2    512

// round-to-nearest-even f32 -> bf16 (inputs are finite)
__device__ __forceinline__ u16 f2bf(float f) {
  unsigned u = __builtin_bit_cast(unsigned, f);
  unsigned r = (u + 0x7fffu + ((u >> 16) & 1u)) >> 16;
  return (u16)r;
}

// ---------------- fp32 -> bf16 weight conversion ----------------
__global__ __launch_bounds__(256) void k_convert(const float* __restrict__ src,
                                                 u16* __restrict__ dst, int n4) {
  int i = blockIdx.x * 256 + threadIdx.x;
  if (i >= n4) return;
  f32x4 v = ((const f32x4*)src)[i];
  ushort4 o;
  o.x = f2bf(v[0]); o.y = f2bf(v[1]); o.z = f2bf(v[2]); o.w = f2bf(v[3]);
  ((ushort4*)dst)[i] = o;
}

// ---------------- gather: build bf16 x[512][2048] ----------------
__global__ __launch_bounds__(256) void k_gather(const int* __restrict__ pairs,
    const float* __restrict__ attrs, const float* __restrict__ h_drug,
    u16* __restrict__ xb) {
  int b = blockIdx.x;
  const float* h0 = h_drug + (size_t)pairs[2 * b] * HD;
  const float* h1 = h_drug + (size_t)pairs[2 * b + 1] * HD;
  u16* xr = xb + (size_t)b * K0;
  for (int i = threadIdx.x; i < HD; i += 256) {
    xr[i] = f2bf(h0[i]);
    xr[1024 + i] = f2bf(h1[i]);
  }
  if (threadIdx.x == 0) {
    xr[1023] = f2bf(attrs[4 * b + 1]);
    xr[2047] = f2bf(attrs[4 * b + 3]);
  }
}

// ---------------- bf16 MFMA GEMM: Y = relu(A[Mx K] * B[N x K]^T + bias) ----------------
// 64x64 block tile, BK=64, 4 waves in 2x2, wave tile 32x32 (2x2 fragments of 16x16x32).
// LDS tiles [64 rows][128 B] with XOR swizzle byte ^= ((row&7)<<4)  (T2).
__global__ __launch_bounds__(256) void k_gemm(
    const u16* __restrict__ A, const u16* __restrict__ B,
    const float* __restrict__ bias, u16* __restrict__ Y, int N, int K) {
  __shared__ char lds[2][16384];  // [buf][ A: 0..8191 | B: 8192..16383 ]
  const int tid = threadIdx.x;
  const int w = tid >> 6, l = tid & 63;
  const int wr = w >> 1, wc = w & 1;
  const int lrow = l & 15;
  const int lk = (l >> 4) << 4;          // byte offset of this lane's k-group
  const int sw = (lrow & 7) << 4;        // row-XOR swizzle (same for all frags: rows differ by 16)
  const size_t K2 = (size_t)K * 2;

  const char* Ag = (const char*)(A + (size_t)blockIdx.y * 64 * K);
  const char* Bg = (const char*)(B + (size_t)blockIdx.x * 64 * K);

  // staging map: thread covers tile bytes o0 = tid*16 and o0+4096 (tile = 64 rows x 128B)
  const int o0 = tid * 16, o1 = o0 + 4096;
  const int r0 = o0 >> 7, c0 = o0 & 127;
  const int r1 = o1 >> 7, c1 = o1 & 127;
  const char* agp0 = Ag + (size_t)r0 * K2 + c0;
  const char* agp1 = Ag + (size_t)r1 * K2 + c1;
  const char* bgp0 = Bg + (size_t)r0 * K2 + c0;
  const char* bgp1 = Bg + (size_t)r1 * K2 + c1;
  const int wo0 = (r0 << 7) + (c0 ^ ((r0 & 7) << 4));
  const int wo1 = (r1 << 7) + (c1 ^ ((r1 & 7) << 4));

  // fragment LDS byte bases (row*128)
  const int aoff = (wr * 32 + lrow) * 128;
  const int boff = (wc * 32 + lrow) * 128;

  f32x4 acc[2][2] = {};
  // prologue: load tile 0 into regs
  f32x4 ra0 = *(const f32x4*)agp0, ra1 = *(const f32x4*)agp1;
  f32x4 rb0 = *(const f32x4*)bgp0, rb1 = *(const f32x4*)bgp1;

  const int NT = K >> 6;
  for (int t = 0; t < NT; ++t) {
    char* buf = lds[t & 1];
    *(f32x4*)(buf + wo0) = ra0;
    *(f32x4*)(buf + wo1) = ra1;
    *(f32x4*)(buf + 8192 + wo0) = rb0;
    *(f32x4*)(buf + 8192 + wo1) = rb1;
    __syncthreads();
    if (t + 1 < NT) {  // prefetch next tile (latency hides under MFMA below)
      const size_t kb = (size_t)(t + 1) * 128;
      ra0 = *(const f32x4*)(agp0 + kb); ra1 = *(const f32x4*)(agp1 + kb);
      rb0 = *(const f32x4*)(bgp0 + kb); rb1 = *(const f32x4*)(bgp1 + kb);
    }
#pragma unroll
    for (int ks = 0; ks < 2; ++ks) {
      const int kq = ((ks << 6) | lk) ^ sw;
      s16x8 a0 = *(const s16x8*)(buf + aoff + kq);
      s16x8 a1 = *(const s16x8*)(buf + aoff + 2048 + kq);
      s16x8 b0 = *(const s16x8*)(buf + 8192 + boff + kq);
      s16x8 b1 = *(const s16x8*)(buf + 8192 + boff + 2048 + kq);
      acc[0][0] = __builtin_amdgcn_mfma_f32_16x16x32_bf16(a0, b0, acc[0][0], 0, 0, 0);
      acc[0][1] = __builtin_amdgcn_mfma_f32_16x16x32_bf16(a0, b1, acc[0][1], 0, 0, 0);
      acc[1][0] = __builtin_amdgcn_mfma_f32_16x16x32_bf16(a1, b0, acc[1][0], 0, 0, 0);
      acc[1][1] = __builtin_amdgcn_mfma_f32_16x16x32_bf16(a1, b1, acc[1][1], 0, 0, 0);
    }
    // no trailing barrier: next iter's barrier (after ds_write to the OTHER buffer)
    // protects this buffer from being overwritten before all waves finish reading it.
  }

  // epilogue: C/D map col=lane&15, row=(lane>>4)*4+reg  [m89]
  const int colb = blockIdx.x * 64 + wc * 32 + lrow;
  const int rowb = blockIdx.y * 64 + wr * 32 + ((l >> 4) << 2);
#pragma unroll
  for (int fb = 0; fb < 2; ++fb) {
    const int col = colb + fb * 16;
    const float bv = bias[col];
#pragma unroll
    for (int fa = 0; fa < 2; ++fa)
#pragma unroll
      for (int r = 0; r < 4; ++r) {
        float v = acc[fa][fb][r] + bv;
        v = v > 0.f ? v : 0.f;
        Y[(size_t)(rowb + fa * 16 + r) * N + col] = f2bf(v);
      }
  }
}

// ---------------- head: per (cell, 64-row tile) MFMA GEMM over that cell's samples ----------
// y3[s, r] = relu( sum_k L0[c,r,k]*y2[s,k] + O0[c,r] );  L0 read exactly once per element.
__global__ __launch_bounds__(256) void k_head(
    const int* __restrict__ cells, const u16* __restrict__ y2b,
    const float* __restrict__ L0, const float* __restrict__ O0,
    float* __restrict__ y3) {
  __shared__ int slist[544];
  __shared__ int scnt;
  __shared__ float red[4][2048];
  const int tid = threadIdx.x;
  const int c = blockIdx.x >> 3, rt = blockIdx.x & 7;
  if (tid == 0) scnt = 0;
  __syncthreads();
  for (int i = tid; i < BATCH; i += 256)
    if (cells[i] == c) slist[atomicAdd(&scnt, 1)] = i;
  __syncthreads();
  const int ns = scnt;
  if (ns == 0) return;
  const int npad = (ns + 31) & ~31;
  for (int i = ns + tid; i < npad; i += 256) slist[i] = slist[0];
  __syncthreads();

  const int w = tid >> 6, l = tid & 63;
  const int lrow = l & 15;
  const int kg = (l >> 4) << 3;  // element offset of this lane's 8-elem k-group
  const int r0 = rt * 64;
  const float* bp[4];
#pragma unroll
  for (int fb = 0; fb < 4; ++fb)
    bp[fb] = L0 + ((size_t)c * N2 + r0 + fb * 16 + lrow) * N1 + w * 256 + kg;

  for (int cb = 0; cb < npad; cb += 32) {
    const u16* ap[2];
#pragma unroll
    for (int fa = 0; fa < 2; ++fa) {
      int s = slist[cb + fa * 16 + lrow];
      ap[fa] = y2b + (size_t)s * N1 + w * 256 + kg;
    }
    f32x4 acc[2][4] = {};
#pragma unroll
    for (int ks = 0; ks < 8; ++ks) {
      s16x8 a0 = *(const s16x8*)(ap[0] + ks * 32);
      s16x8 a1 = *(const s16x8*)(ap[1] + ks * 32);
#pragma unroll
      for (int fb = 0; fb < 4; ++fb) {
        f32x4 f0 = *(const f32x4*)(bp[fb] + ks * 32);
        f32x4 f1 = *(const f32x4*)(bp[fb] + ks * 32 + 4);
        s16x8 bb;
        bb[0] = (short)f2bf(f0[0]); bb[1] = (short)f2bf(f0[1]);
        bb[2] = (short)f2bf(f0[2]); bb[3] = (short)f2bf(f0[3]);
        bb[4] = (short)f2bf(f1[0]); bb[5] = (short)f2bf(f1[1]);
        bb[6] = (short)f2bf(f1[2]); bb[7] = (short)f2bf(f1[3]);
        acc[0][fb] = __builtin_amdgcn_mfma_f32_16x16x32_bf16(a0, bb, acc[0][fb], 0, 0, 0);
        acc[1][fb] = __builtin_amdgcn_mfma_f32_16x16x32_bf16(a1, bb, acc[1][fb], 0, 0, 0);
      }
    }
    __syncthreads();  // red free (previous chunk's epilogue readers done)
#pragma unroll
    for (int fa = 0; fa < 2; ++fa)
#pragma unroll
      for (int fb = 0; fb < 4; ++fb)
#pragma unroll
        for (int r = 0; r < 4; ++r) {
          int s = fa * 16 + (l >> 4) * 4 + r;
          red[w][s * 64 + fb * 16 + lrow] = acc[fa][fb][r];
        }
    __syncthreads();
    for (int e = tid; e < 2048; e += 256) {
      int s = e >> 6, r = e & 63;
      if (cb + s < ns) {
        float v = red[0][e] + red[1][e] + red[2][e] + red[3][e] +
                  O0[(size_t)c * N2 + r0 + r];
        y3[(size_t)slist[cb + s] * N2 + r0 + r] = v > 0.f ? v : 0.f;
      }
    }
  }
}

// ---------------- final: out[b] = sum_r y3[b,r]*L1[c,r] + O1[c] ----------------
__global__ __launch_bounds__(64) void k_final(
    const int* __restrict__ cells, const float* __restrict__ y3,
    const float* __restrict__ L1, const float* __restrict__ O1,
    float* __restrict__ out) {
  const int b = blockIdx.x, l = threadIdx.x;
  const int c = cells[b];
  const float* yr = y3 + (size_t)b * N2;
  const float* lc = L1 + (size_t)c * N2;
  float acc = 0.f;
#pragma unroll
  for (int i = 0; i < N2 / 64; ++i) acc += yr[l + i * 64] * lc[l + i * 64];
#pragma unroll
  for (int off = 32; off; off >>= 1) acc += __shfl_xor(acc, off, 64);
  if (l == 0) out[b] = acc + O1[c];
}

// ---------------- launch ----------------
extern "C" void kernel_launch(void* const* d_in, const int* in_sizes, int n_in,
                              void* d_out, int out_size, void* d_ws, size_t ws_size,
                              hipStream_t stream) {
  const int*   pairs  = (const int*)d_in[0];
  const int*   cells  = (const int*)d_in[1];
  const float* attrs  = (const float*)d_in[2];
  const float* h_drug = (const float*)d_in[3];
  const float* W0     = (const float*)d_in[4];
  const float* b0     = (const float*)d_in[5];
  const float* W1     = (const float*)d_in[6];
  const float* b1     = (const float*)d_in[7];
  const float* L0     = (const float*)d_in[8];
  const float* O0     = (const float*)d_in[9];
  const float* L1     = (const float*)d_in[10];
  const float* O1     = (const float*)d_in[11];
  float* out = (float*)d_out;

  char* ws = (char*)d_ws;
  u16*   xb  = (u16*)(ws);                          // 2 MB  512x2048 bf16
  u16*   w0b = (u16*)(ws + (2u  << 20));            // 8 MB  2048x2048 bf16
  u16*   w1b = (u16*)(ws + (10u << 20));            // 4 MB  1024x2048 bf16
  u16*   y1b = (u16*)(ws + (14u << 20));            // 2 MB  512x2048 bf16
  u16*   y2b = (u16*)(ws + (16u << 20));            // 1 MB  512x1024 bf16
  float* y3  = (float*)(ws + (17u << 20));          // 1 MB  512x512 f32

  k_convert<<<4096, 256, 0, stream>>>(W0, w0b, (N0 * K0) / 4);
  k_convert<<<2048, 256, 0, stream>>>(W1, w1b, (N1 * K0) / 4);
  k_gather<<<BATCH, 256, 0, stream>>>(pairs, attrs, h_drug, xb);
  k_gemm<<<dim3(N0 / 64, BATCH / 64), 256, 0, stream>>>(xb, w0b, b0, y1b, N0, K0);
  k_gemm<<<dim3(N1 / 64, BATCH / 64), 256, 0, stream>>>(y1b, w1b, b1, y2b, N1, K0);
  k_head<<<256, 256, 0, stream>>>(cells, y2b, L0, O0, y3);
  k_final<<<BATCH, 64, 0, stream>>>(cells, y3, L1, O1, out);
}

// Round 3
// 71.673 us; speedup vs baseline: 5.1424x; 1.0064x over previous
//
#include <hip/hip_runtime.h>

typedef short s16x8 __attribute__((ext_vector_type(8)));
typedef float f32x4 __attribute__((ext_vector_type(4)));
typedef unsigned short u16;

#define BATCH 512
#define HD    1023
#define K0    2048
#define N0    2048
#define N1    1024
#define N2    512

// round-to-nearest-even f32 -> bf16 (inputs finite)
__device__ __forceinline__ u16 f2bf(float f) {
  unsigned u = __builtin_bit_cast(unsigned, f);
  unsigned r = (u + 0x7fffu + ((u >> 16) & 1u)) >> 16;
  return (u16)r;
}

__device__ __forceinline__ s16x8 pack8(f32x4 a, f32x4 b) {
  s16x8 r;
  r[0] = (short)f2bf(a[0]); r[1] = (short)f2bf(a[1]);
  r[2] = (short)f2bf(a[2]); r[3] = (short)f2bf(a[3]);
  r[4] = (short)f2bf(b[0]); r[5] = (short)f2bf(b[1]);
  r[6] = (short)f2bf(b[2]); r[7] = (short)f2bf(b[3]);
  return r;
}

// ---------------- gather: build bf16 x[512][2048] ----------------
__global__ __launch_bounds__(256) void k_gather(const int* __restrict__ pairs,
    const float* __restrict__ attrs, const float* __restrict__ h_drug,
    u16* __restrict__ xb) {
  int b = blockIdx.x;
  const float* h0 = h_drug + (size_t)pairs[2 * b] * HD;
  const float* h1 = h_drug + (size_t)pairs[2 * b + 1] * HD;
  u16* xr = xb + (size_t)b * K0;
  for (int i = threadIdx.x; i < HD; i += 256) {
    xr[i] = f2bf(h0[i]);
    xr[1024 + i] = f2bf(h1[i]);
  }
  if (threadIdx.x == 0) {
    xr[1023] = f2bf(attrs[4 * b + 1]);
    xr[2047] = f2bf(attrs[4 * b + 3]);
  }
}

// ---------------- bf16 MFMA GEMM with fused W f32->bf16 conversion ----------------
// Y = relu(A[512 x K] * W[N x K]^T + bias), A bf16, W f32, Y bf16.
// Block tile 64 x BNROWS, BK=64. 4 waves. LDS XOR-swizzled (T2), double-buffered,
// register prefetch. XCD-aware block map: each XCD owns (N/BNROWS)/8 B-panels (T1).
template <int BNROWS>
__global__ __launch_bounds__(256, 2) void k_gemm(
    const u16* __restrict__ A, const float* __restrict__ W,
    const float* __restrict__ bias, u16* __restrict__ Y, int N, int K) {
  constexpr int BF = BNROWS / 32;        // B fragments per wave (2 or 1)
  constexpr int BBYTES = BNROWS * 128;   // bf16 B tile bytes
  __shared__ char lds[2][8192 + BBYTES];
  const int tid = threadIdx.x;
  const int w = tid >> 6, l = tid & 63;
  const int wr = w >> 1, wc = w & 1;
  const int lrow = l & 15;
  const int lk = (l >> 4) << 4;
  const int sw = (lrow & 7) << 4;

  // XCD swizzle: consecutive blockIdx round-robin XCDs; give each XCD a
  // contiguous wgid chunk = few bn panels x all 8 bm.
  const int nwg = gridDim.x;
  const int wgid = (blockIdx.x & 7) * (nwg >> 3) + (blockIdx.x >> 3);
  const int bn = wgid >> 3, bm = wgid & 7;

  const size_t K2 = (size_t)K * 2;
  const char* Ag = (const char*)A + (size_t)bm * 64 * K2;
  const float* Wg = W + (size_t)bn * BNROWS * K;

  // A staging (bf16 copy): thread covers tile bytes tid*16 and tid*16+4096
  const int o0 = tid * 16, o1 = o0 + 4096;
  const int ar0 = o0 >> 7, ac0 = o0 & 127;
  const int ar1 = o1 >> 7, ac1 = o1 & 127;
  const char* agp0 = Ag + (size_t)ar0 * K2 + ac0;
  const char* agp1 = Ag + (size_t)ar1 * K2 + ac1;
  const int awo0 = (ar0 << 7) + (ac0 ^ ((ar0 & 7) << 4));
  const int awo1 = (ar1 << 7) + (ac1 ^ ((ar1 & 7) << 4));

  // B staging (f32 -> bf16): BF==2: 16 floats/thread; BF==1: 8 floats/thread
  const int br = (BF == 2) ? (tid >> 2) : (tid >> 3);
  const int bq = (BF == 2) ? (tid & 3) : (tid & 7);
  const float* wgp = Wg + (size_t)br * K + bq * (BF == 2 ? 16 : 8);
  const int bsw = (br & 7) << 4;
  const int bwo0 = (br << 7) + (((BF == 2 ? bq * 32 : bq * 16)) ^ bsw);
  const int bwo1 = (br << 7) + ((bq * 32 + 16) ^ bsw);  // BF==2 only

  const int aoff = (wr * 32 + lrow) * 128;
  const int boff = (wc * 16 * BF + lrow) * 128;

  f32x4 acc[2][BF] = {};

  // prologue
  f32x4 ra0 = *(const f32x4*)agp0, ra1 = *(const f32x4*)agp1;
  f32x4 rw0 = *(const f32x4*)(wgp + 0), rw1 = *(const f32x4*)(wgp + 4);
  f32x4 rw2 = {}, rw3 = {};
  if constexpr (BF == 2) { rw2 = *(const f32x4*)(wgp + 8); rw3 = *(const f32x4*)(wgp + 12); }

  const int NT = K >> 6;
  for (int t = 0; t < NT; ++t) {
    char* buf = lds[t & 1];
    *(f32x4*)(buf + awo0) = ra0;
    *(f32x4*)(buf + awo1) = ra1;
    *(s16x8*)(buf + 8192 + bwo0) = pack8(rw0, rw1);
    if constexpr (BF == 2) *(s16x8*)(buf + 8192 + bwo1) = pack8(rw2, rw3);
    __syncthreads();
    if (t + 1 < NT) {  // prefetch next tile into registers
      const size_t ab = (size_t)(t + 1) * 128;
      const int wf = (t + 1) * 64;
      ra0 = *(const f32x4*)(agp0 + ab); ra1 = *(const f32x4*)(agp1 + ab);
      rw0 = *(const f32x4*)(wgp + wf); rw1 = *(const f32x4*)(wgp + wf + 4);
      if constexpr (BF == 2) {
        rw2 = *(const f32x4*)(wgp + wf + 8); rw3 = *(const f32x4*)(wgp + wf + 12);
      }
    }
#pragma unroll
    for (int ks = 0; ks < 2; ++ks) {
      const int kq = ((ks << 6) | lk) ^ sw;
      s16x8 a0 = *(const s16x8*)(buf + aoff + kq);
      s16x8 a1 = *(const s16x8*)(buf + aoff + 2048 + kq);
      s16x8 b0 = *(const s16x8*)(buf + 8192 + boff + kq);
      acc[0][0] = __builtin_amdgcn_mfma_f32_16x16x32_bf16(a0, b0, acc[0][0], 0, 0, 0);
      acc[1][0] = __builtin_amdgcn_mfma_f32_16x16x32_bf16(a1, b0, acc[1][0], 0, 0, 0);
      if constexpr (BF == 2) {
        s16x8 b1 = *(const s16x8*)(buf + 8192 + boff + 2048 + kq);
        acc[0][1] = __builtin_amdgcn_mfma_f32_16x16x32_bf16(a0, b1, acc[0][1], 0, 0, 0);
        acc[1][1] = __builtin_amdgcn_mfma_f32_16x16x32_bf16(a1, b1, acc[1][1], 0, 0, 0);
      }
    }
    // next iter's barrier (after writes to the OTHER buffer) protects this buffer
  }

  // epilogue: C/D map col=lane&15, row=(lane>>4)*4+reg
  const int colb = bn * BNROWS + wc * 16 * BF + lrow;
  const int rowb = bm * 64 + wr * 32 + ((l >> 4) << 2);
#pragma unroll
  for (int fb = 0; fb < BF; ++fb) {
    const int col = colb + fb * 16;
    const float bv = bias[col];
#pragma unroll
    for (int fa = 0; fa < 2; ++fa)
#pragma unroll
      for (int r = 0; r < 4; ++r) {
        float v = acc[fa][fb][r] + bv;
        v = v > 0.f ? v : 0.f;
        Y[(size_t)(rowb + fa * 16 + r) * N + col] = f2bf(v);
      }
  }
}

// ---------------- head: per (cell, 64-row tile) MFMA over that cell's samples ------------
// Computes y3[s, r] = relu(L0[c,r,:] . y2[s,:] + O0[c,r]) for its 64 rows, then folds the
// L1 dot: pp[rt*512 + s] = sum_r y3[s,r] * L1[c, r0+r].  L0 read exactly once per element.
// 8 waves split K (128 each) for latency hiding of the L0 stream.
__global__ __launch_bounds__(512) void k_head(
    const int* __restrict__ cells, const u16* __restrict__ y2b,
    const float* __restrict__ L0, const float* __restrict__ O0,
    const float* __restrict__ L1, float* __restrict__ pp) {
  __shared__ int slist[544];
  __shared__ int scnt;
  __shared__ float red[8][2048];
  const int tid = threadIdx.x;
  const int c = blockIdx.x >> 3, rt = blockIdx.x & 7;
  if (tid == 0) scnt = 0;
  __syncthreads();
  for (int i = tid; i < BATCH; i += 512)
    if (cells[i] == c) slist[atomicAdd(&scnt, 1)] = i;
  __syncthreads();
  const int ns = scnt;
  if (ns == 0) return;
  const int npad = (ns + 31) & ~31;
  for (int i = ns + tid; i < npad; i += 512) slist[i] = slist[0];
  __syncthreads();

  const int w = tid >> 6, l = tid & 63;
  const int lrow = l & 15;
  const int kg = (l >> 4) << 3;
  const int r0 = rt * 64;
  const float* bp[4];
#pragma unroll
  for (int fb = 0; fb < 4; ++fb)
    bp[fb] = L0 + ((size_t)c * N2 + r0 + fb * 16 + lrow) * N1 + w * 128 + kg;

  for (int cb = 0; cb < npad; cb += 32) {
    const u16* ap0 = y2b + (size_t)slist[cb + lrow] * N1 + w * 128 + kg;
    const u16* ap1 = y2b + (size_t)slist[cb + 16 + lrow] * N1 + w * 128 + kg;
    f32x4 acc[2][4] = {};
#pragma unroll
    for (int ks = 0; ks < 4; ++ks) {
      s16x8 a0 = *(const s16x8*)(ap0 + ks * 32);
      s16x8 a1 = *(const s16x8*)(ap1 + ks * 32);
#pragma unroll
      for (int fb = 0; fb < 4; ++fb) {
        f32x4 f0 = *(const f32x4*)(bp[fb] + ks * 32);
        f32x4 f1 = *(const f32x4*)(bp[fb] + ks * 32 + 4);
        s16x8 bb = pack8(f0, f1);
        acc[0][fb] = __builtin_amdgcn_mfma_f32_16x16x32_bf16(a0, bb, acc[0][fb], 0, 0, 0);
        acc[1][fb] = __builtin_amdgcn_mfma_f32_16x16x32_bf16(a1, bb, acc[1][fb], 0, 0, 0);
      }
    }
    __syncthreads();  // previous chunk's epilogue readers done with red
#pragma unroll
    for (int fa = 0; fa < 2; ++fa)
#pragma unroll
      for (int fb = 0; fb < 4; ++fb)
#pragma unroll
        for (int r = 0; r < 4; ++r) {
          int s = fa * 16 + (l >> 4) * 4 + r;
          red[w][s * 64 + fb * 16 + lrow] = acc[fa][fb][r];
        }
    __syncthreads();
    // epilogue: sum 8 wave partials, +O0, relu, dot with L1 -> pp
    {
      const int s = tid >> 4;        // 0..31
      const int rq = (tid & 15) * 4; // 4 rows per thread
      if (cb + s < ns) {             // uniform within each 16-lane group
        float p = 0.f;
#pragma unroll
        for (int j = 0; j < 4; ++j) {
          const int r = rq + j, e = s * 64 + r;
          float v = red[0][e] + red[1][e] + red[2][e] + red[3][e] +
                    red[4][e] + red[5][e] + red[6][e] + red[7][e] +
                    O0[(size_t)c * N2 + r0 + r];
          v = v > 0.f ? v : 0.f;
          p += v * L1[(size_t)c * N2 + r0 + r];
        }
#pragma unroll
        for (int off = 8; off; off >>= 1) p += __shfl_xor(p, off, 16);
        if ((tid & 15) == 0) pp[(size_t)rt * BATCH + slist[cb + s]] = p;
      }
    }
  }
}

// ---------------- final: out[b] = sum_rt pp[rt][b] + O1[c] ----------------
__global__ __launch_bounds__(512) void k_final(
    const int* __restrict__ cells, const float* __restrict__ pp,
    const float* __restrict__ O1, float* __restrict__ out) {
  const int b = threadIdx.x;
  float s = O1[cells[b]];
#pragma unroll
  for (int rt = 0; rt < 8; ++rt) s += pp[(size_t)rt * BATCH + b];
  out[b] = s;
}

// ---------------- launch ----------------
extern "C" void kernel_launch(void* const* d_in, const int* in_sizes, int n_in,
                              void* d_out, int out_size, void* d_ws, size_t ws_size,
                              hipStream_t stream) {
  const int*   pairs  = (const int*)d_in[0];
  const int*   cells  = (const int*)d_in[1];
  const float* attrs  = (const float*)d_in[2];
  const float* h_drug = (const float*)d_in[3];
  const float* W0     = (const float*)d_in[4];
  const float* b0     = (const float*)d_in[5];
  const float* W1     = (const float*)d_in[6];
  const float* b1     = (const float*)d_in[7];
  const float* L0     = (const float*)d_in[8];
  const float* O0     = (const float*)d_in[9];
  const float* L1     = (const float*)d_in[10];
  const float* O1     = (const float*)d_in[11];
  float* out = (float*)d_out;

  char* ws = (char*)d_ws;
  u16*   xb  = (u16*)(ws);                 // 2 MB  512x2048 bf16
  u16*   y1b = (u16*)(ws + (2u << 20));    // 2 MB  512x2048 bf16
  u16*   y2b = (u16*)(ws + (4u << 20));    // 1 MB  512x1024 bf16
  float* pp  = (float*)(ws + (5u << 20));  // 16 KB 8x512 f32

  k_gather<<<BATCH, 256, 0, stream>>>(pairs, attrs, h_drug, xb);
  k_gemm<64><<<256, 256, 0, stream>>>(xb, W0, b0, y1b, N0, K0);
  k_gemm<32><<<256, 256, 0, stream>>>(y1b, W1, b1, y2b, N1, K0);
  k_head<<<256, 512, 0, stream>>>(cells, y2b, L0, O0, L1, pp);
  k_final<<<1, 512, 0, stream>>>(cells, pp, O1, out);
}

// Round 4
// 61.652 us; speedup vs baseline: 5.9781x; 1.1625x over previous
//
#include <hip/hip_runtime.h>

typedef short s16x8 __attribute__((ext_vector_type(8)));
typedef float f32x4 __attribute__((ext_vector_type(4)));
typedef unsigned short u16;

#define BATCH 512
#define HD    1023
#define K0    2048
#define N0    2048
#define N1    1024
#define N2    512

// round-to-nearest-even f32 -> bf16 (inputs finite)
__device__ __forceinline__ u16 f2bf(float f) {
  unsigned u = __builtin_bit_cast(unsigned, f);
  unsigned r = (u + 0x7fffu + ((u >> 16) & 1u)) >> 16;
  return (u16)r;
}

__device__ __forceinline__ s16x8 pack8(f32x4 a, f32x4 b) {
  s16x8 r;
  r[0] = (short)f2bf(a[0]); r[1] = (short)f2bf(a[1]);
  r[2] = (short)f2bf(a[2]); r[3] = (short)f2bf(a[3]);
  r[4] = (short)f2bf(b[0]); r[5] = (short)f2bf(b[1]);
  r[6] = (short)f2bf(b[2]); r[7] = (short)f2bf(b[3]);
  return r;
}

// ---------------- gather: build bf16 x[512][2048] ----------------
__global__ __launch_bounds__(256) void k_gather(const int* __restrict__ pairs,
    const float* __restrict__ attrs, const float* __restrict__ h_drug,
    u16* __restrict__ xb) {
  int b = blockIdx.x;
  const float* h0 = h_drug + (size_t)pairs[2 * b] * HD;
  const float* h1 = h_drug + (size_t)pairs[2 * b + 1] * HD;
  u16* xr = xb + (size_t)b * K0;
  for (int i = threadIdx.x; i < HD; i += 256) {
    xr[i] = f2bf(h0[i]);
    xr[1024 + i] = f2bf(h1[i]);
  }
  if (threadIdx.x == 0) {
    xr[1023] = f2bf(attrs[4 * b + 1]);
    xr[2047] = f2bf(attrs[4 * b + 3]);
  }
}

// ---------------- bf16 MFMA GEMM, fused W f32->bf16, 4-deep prefetch pipeline ----------
// Y = relu(A[512 x K] * W[N x K]^T + bias). Block tile BM x 64, BK=64, 4 waves (2x2).
// LDS XOR-swizzle (T2); raw s_barrier + lgkmcnt(0) only (no vmcnt drain in loop, T4).
#define G_ISSUE(s, t) { \
  const size_t ab = (size_t)(t) * 128; const int wf = (t) * 64; \
  pa0_##s = *(const s16x8*)(agp0 + ab); \
  if constexpr (AF == 2) pa1_##s = *(const s16x8*)(agp1 + ab); \
  pw0_##s = *(const f32x4*)(wgp + wf);     pw1_##s = *(const f32x4*)(wgp + wf + 4); \
  pw2_##s = *(const f32x4*)(wgp + wf + 8); pw3_##s = *(const f32x4*)(wgp + wf + 12); }

#define G_STAGE(s, t, DOLOAD) { \
  char* buf = lds[(s) & 1]; \
  *(s16x8*)(buf + awo0) = pa0_##s; \
  if constexpr (AF == 2) *(s16x8*)(buf + awo1) = pa1_##s; \
  *(s16x8*)(buf + ABYTES + bwo0) = pack8(pw0_##s, pw1_##s); \
  *(s16x8*)(buf + ABYTES + bwo1) = pack8(pw2_##s, pw3_##s); \
  asm volatile("s_waitcnt lgkmcnt(0)" ::: "memory"); \
  __builtin_amdgcn_s_barrier(); \
  asm volatile("" ::: "memory"); \
  if (DOLOAD) G_ISSUE(s, (t) + 4) \
  _Pragma("unroll") \
  for (int ks = 0; ks < 2; ++ks) { \
    const int kq = ((ks << 6) | lk) ^ sw; \
    s16x8 b0 = *(const s16x8*)(buf + ABYTES + boff + kq); \
    s16x8 b1 = *(const s16x8*)(buf + ABYTES + boff + 2048 + kq); \
    s16x8 a0 = *(const s16x8*)(buf + aoff + kq); \
    acc[0][0] = __builtin_amdgcn_mfma_f32_16x16x32_bf16(a0, b0, acc[0][0], 0, 0, 0); \
    acc[0][1] = __builtin_amdgcn_mfma_f32_16x16x32_bf16(a0, b1, acc[0][1], 0, 0, 0); \
    if constexpr (AF == 2) { \
      s16x8 a1 = *(const s16x8*)(buf + aoff + 2048 + kq); \
      acc[1][0] = __builtin_amdgcn_mfma_f32_16x16x32_bf16(a1, b0, acc[1][0], 0, 0, 0); \
      acc[1][1] = __builtin_amdgcn_mfma_f32_16x16x32_bf16(a1, b1, acc[1][1], 0, 0, 0); \
    } \
  } }

template <int BM>
__global__ __launch_bounds__(256) void k_gemm(
    const u16* __restrict__ A, const float* __restrict__ W,
    const float* __restrict__ bias, u16* __restrict__ Y, int N, int K) {
  constexpr int AF = BM / 32;            // A fragments per wave
  constexpr int ABYTES = BM * 128;       // A tile bytes (bf16, 64 k)
  constexpr int NBMSH = (BM == 64) ? 3 : 4;
  __shared__ char lds[2][ABYTES + 8192];
  const int tid = threadIdx.x;
  const int w = tid >> 6, l = tid & 63;
  const int wr = w >> 1, wc = w & 1;
  const int lrow = l & 15;
  const int lk = (l >> 4) << 4;
  const int sw = (lrow & 7) << 4;

  // XCD-aware swizzle (grid=256): each XCD gets contiguous wgid chunk
  const int wgid = (blockIdx.x & 7) * (gridDim.x >> 3) + (blockIdx.x >> 3);
  const int bn = wgid >> NBMSH, bm = wgid & ((1 << NBMSH) - 1);

  const size_t K2 = (size_t)K * 2;
  const char* Ag = (const char*)A + (size_t)bm * BM * K2;
  const float* Wg = W + (size_t)bn * 64 * K;

  // A staging map (bf16 copy, 16B/slot)
  const int o0 = tid * 16;
  const int ar0 = o0 >> 7, ac0 = o0 & 127;
  const char* agp0 = Ag + (size_t)ar0 * K2 + ac0;
  const int awo0 = (ar0 << 7) + (ac0 ^ ((ar0 & 7) << 4));
  const int o1 = o0 + 4096;
  const int ar1 = o1 >> 7, ac1 = o1 & 127;
  const char* agp1 = Ag + (size_t)ar1 * K2 + ac1;  // only used if AF==2
  const int awo1 = (ar1 << 7) + (ac1 ^ ((ar1 & 7) << 4));

  // W staging map (f32 -> bf16): row tid>>2, 16 floats at col (tid&3)*16
  const int br = tid >> 2, bq = tid & 3;
  const float* wgp = Wg + (size_t)br * K + bq * 16;
  const int bsw = (br & 7) << 4;
  const int bwo0 = (br << 7) + ((bq * 32) ^ bsw);
  const int bwo1 = (br << 7) + ((bq * 32 + 16) ^ bsw);

  const int aoff = (wr * (BM / 2) + lrow) * 128;
  const int boff = (wc * 32 + lrow) * 128;

  f32x4 acc[AF][2] = {};
  s16x8 pa0_0, pa0_1, pa0_2, pa0_3;
  s16x8 pa1_0, pa1_1, pa1_2, pa1_3;
  f32x4 pw0_0, pw1_0, pw2_0, pw3_0;
  f32x4 pw0_1, pw1_1, pw2_1, pw3_1;
  f32x4 pw0_2, pw1_2, pw2_2, pw3_2;
  f32x4 pw0_3, pw1_3, pw2_3, pw3_3;

  G_ISSUE(0, 0) G_ISSUE(1, 1) G_ISSUE(2, 2) G_ISSUE(3, 3)
  const int NT = K >> 6;  // 32
  int t = 0;
  for (; t < NT - 4; t += 4) {
    G_STAGE(0, t, 1) G_STAGE(1, t + 1, 1) G_STAGE(2, t + 2, 1) G_STAGE(3, t + 3, 1)
  }
  G_STAGE(0, t, 0) G_STAGE(1, t + 1, 0) G_STAGE(2, t + 2, 0) G_STAGE(3, t + 3, 0)

  // epilogue: C/D map col=lane&15, row=(lane>>4)*4+reg
  const int colb = bn * 64 + wc * 32 + lrow;
  const int rowb = bm * BM + wr * (BM / 2) + ((l >> 4) << 2);
#pragma unroll
  for (int fb = 0; fb < 2; ++fb) {
    const int col = colb + fb * 16;
    const float bv = bias[col];
#pragma unroll
    for (int fa = 0; fa < AF; ++fa)
#pragma unroll
      for (int r = 0; r < 4; ++r) {
        float v = acc[fa][fb][r] + bv;
        v = v > 0.f ? v : 0.f;
        Y[(size_t)(rowb + fa * 16 + r) * N + col] = f2bf(v);
      }
  }
}

// ---------------- head: per (cell, 64-row tile); LDS-staged coalesced L0 ----------------
#define H_ISSUE(S, ch) { \
  const float* src = hsrc + (ch) * 256; \
  q0_##S = *(const f32x4*)(src);      q1_##S = *(const f32x4*)(src + 4); \
  q2_##S = *(const f32x4*)(src + 8);  q3_##S = *(const f32x4*)(src + 12); \
  q4_##S = *(const f32x4*)(src + 16); q5_##S = *(const f32x4*)(src + 20); \
  q6_##S = *(const f32x4*)(src + 24); q7_##S = *(const f32x4*)(src + 28); }

#define H_WRITE(S, ch) { \
  char* dst = lbuf[(ch) & 1] + (hrow << 9); \
  *(s16x8*)(dst + ((hcb + 0)  ^ hswz)) = pack8(q0_##S, q1_##S); \
  *(s16x8*)(dst + ((hcb + 16) ^ hswz)) = pack8(q2_##S, q3_##S); \
  *(s16x8*)(dst + ((hcb + 32) ^ hswz)) = pack8(q4_##S, q5_##S); \
  *(s16x8*)(dst + ((hcb + 48) ^ hswz)) = pack8(q6_##S, q7_##S); }

#define H_SYNC { \
  asm volatile("s_waitcnt lgkmcnt(0)" ::: "memory"); \
  __builtin_amdgcn_s_barrier(); \
  asm volatile("" ::: "memory"); }

#define H_MFMA(ch) { \
  const char* bb = lbuf[(ch) & 1]; \
  s16x8 bv0 = *(const s16x8*)(bb + ((0 * 16 + lrow) << 9) + kboff); \
  s16x8 bv1 = *(const s16x8*)(bb + ((1 * 16 + lrow) << 9) + kboff); \
  s16x8 bv2 = *(const s16x8*)(bb + ((2 * 16 + lrow) << 9) + kboff); \
  s16x8 bv3 = *(const s16x8*)(bb + ((3 * 16 + lrow) << 9) + kboff); \
  s16x8 av0 = *(const s16x8*)(ap0 + (ch) * 256); \
  s16x8 av1 = *(const s16x8*)(ap1 + (ch) * 256); \
  acc[0][0] = __builtin_amdgcn_mfma_f32_16x16x32_bf16(av0, bv0, acc[0][0], 0, 0, 0); \
  acc[0][1] = __builtin_amdgcn_mfma_f32_16x16x32_bf16(av0, bv1, acc[0][1], 0, 0, 0); \
  acc[0][2] = __builtin_amdgcn_mfma_f32_16x16x32_bf16(av0, bv2, acc[0][2], 0, 0, 0); \
  acc[0][3] = __builtin_amdgcn_mfma_f32_16x16x32_bf16(av0, bv3, acc[0][3], 0, 0, 0); \
  acc[1][0] = __builtin_amdgcn_mfma_f32_16x16x32_bf16(av1, bv0, acc[1][0], 0, 0, 0); \
  acc[1][1] = __builtin_amdgcn_mfma_f32_16x16x32_bf16(av1, bv1, acc[1][1], 0, 0, 0); \
  acc[1][2] = __builtin_amdgcn_mfma_f32_16x16x32_bf16(av1, bv2, acc[1][2], 0, 0, 0); \
  acc[1][3] = __builtin_amdgcn_mfma_f32_16x16x32_bf16(av1, bv3, acc[1][3], 0, 0, 0); }

__global__ __launch_bounds__(512) void k_head(
    const int* __restrict__ cells, const u16* __restrict__ y2b,
    const float* __restrict__ L0, const float* __restrict__ O0,
    const float* __restrict__ L1, float* __restrict__ pp) {
  __shared__ int slist[544];
  __shared__ int scnt;
  __shared__ float red[8][2048];      // 64 KB
  __shared__ char lbuf[2][32768];     // 64 KB: 64 rows x 512 B (bf16), XOR-swizzled
  const int tid = threadIdx.x;
  const int c = blockIdx.x >> 3, rt = blockIdx.x & 7;
  if (tid == 0) scnt = 0;
  __syncthreads();
  for (int i = tid; i < BATCH; i += 512)
    if (cells[i] == c) slist[atomicAdd(&scnt, 1)] = i;
  __syncthreads();
  const int ns = scnt;
  if (ns == 0) return;
  const int npad = (ns + 31) & ~31;
  for (int i = ns + tid; i < npad; i += 512) slist[i] = slist[0];
  __syncthreads();

  const int w = tid >> 6, l = tid & 63;
  const int lrow = l & 15;
  const int r0 = rt * 64;
  const float* L0c = L0 + ((size_t)c * N2 + r0) * N1;
  // staging map: row tid>>3 (0..63), 32 floats at col (tid&7)*32 -> 1KB-contiguous/8 threads
  const int hrow = tid >> 3;
  const int hcb = (tid & 7) * 64;                 // byte col in bf16 row
  const int hswz = (hrow & 7) << 4;
  const float* hsrc = L0c + (size_t)hrow * N1 + (tid & 7) * 32;
  // MFMA B-frag read offset within row: wave k-slice w*32 elems + lane group
  const int kboff = ((w * 64 + ((l >> 4) << 4)) ^ ((lrow & 7) << 4));

  f32x4 q0_A, q1_A, q2_A, q3_A, q4_A, q5_A, q6_A, q7_A;
  f32x4 q0_B, q1_B, q2_B, q3_B, q4_B, q5_B, q6_B, q7_B;

  for (int cb = 0; cb < npad; cb += 32) {
    const u16* ap0 = y2b + (size_t)slist[cb + lrow] * N1 + w * 32 + ((l >> 4) << 3);
    const u16* ap1 = y2b + (size_t)slist[cb + 16 + lrow] * N1 + w * 32 + ((l >> 4) << 3);
    f32x4 acc[2][4] = {};
    H_ISSUE(A, 0)
    H_WRITE(A, 0)
    H_ISSUE(B, 1)
    H_SYNC
    H_MFMA(0)
    H_WRITE(B, 1)
    H_ISSUE(A, 2)
    H_SYNC
    H_MFMA(1)
    H_WRITE(A, 2)
    H_ISSUE(B, 3)
    H_SYNC
    H_MFMA(2)
    H_WRITE(B, 3)
    H_SYNC
    H_MFMA(3)

    __syncthreads();  // all MFMA done; red free (prev pass readers done)
#pragma unroll
    for (int h = 0; h < 2; ++h)
#pragma unroll
      for (int fb = 0; fb < 4; ++fb)
#pragma unroll
        for (int r = 0; r < 4; ++r) {
          int s = h * 16 + (l >> 4) * 4 + r;
          red[w][s * 64 + fb * 16 + lrow] = acc[h][fb][r];
        }
    __syncthreads();
    {
      const int s = tid >> 4;         // 0..31
      const int rq = (tid & 15) * 4;  // 4 rows/thread
      if (cb + s < ns) {
        float p = 0.f;
#pragma unroll
        for (int j = 0; j < 4; ++j) {
          const int r = rq + j, e = s * 64 + r;
          float v = red[0][e] + red[1][e] + red[2][e] + red[3][e] +
                    red[4][e] + red[5][e] + red[6][e] + red[7][e] +
                    O0[(size_t)c * N2 + r0 + r];
          v = v > 0.f ? v : 0.f;
          p += v * L1[(size_t)c * N2 + r0 + r];
        }
#pragma unroll
        for (int off = 8; off; off >>= 1) p += __shfl_xor(p, off, 16);
        if ((tid & 15) == 0) pp[(size_t)rt * BATCH + slist[cb + s]] = p;
      }
    }
  }
}

// ---------------- final: out[b] = sum_rt pp[rt][b] + O1[c] ----------------
__global__ __launch_bounds__(512) void k_final(
    const int* __restrict__ cells, const float* __restrict__ pp,
    const float* __restrict__ O1, float* __restrict__ out) {
  const int b = threadIdx.x;
  float s = O1[cells[b]];
#pragma unroll
  for (int rt = 0; rt < 8; ++rt) s += pp[(size_t)rt * BATCH + b];
  out[b] = s;
}

// ---------------- launch ----------------
extern "C" void kernel_launch(void* const* d_in, const int* in_sizes, int n_in,
                              void* d_out, int out_size, void* d_ws, size_t ws_size,
                              hipStream_t stream) {
  const int*   pairs  = (const int*)d_in[0];
  const int*   cells  = (const int*)d_in[1];
  const float* attrs  = (const float*)d_in[2];
  const float* h_drug = (const float*)d_in[3];
  const float* W0     = (const float*)d_in[4];
  const float* b0     = (const float*)d_in[5];
  const float* W1     = (const float*)d_in[6];
  const float* b1     = (const float*)d_in[7];
  const float* L0     = (const float*)d_in[8];
  const float* O0     = (const float*)d_in[9];
  const float* L1     = (const float*)d_in[10];
  const float* O1     = (const float*)d_in[11];
  float* out = (float*)d_out;

  char* ws = (char*)d_ws;
  u16*   xb  = (u16*)(ws);                 // 2 MB  512x2048 bf16
  u16*   y1b = (u16*)(ws + (2u << 20));    // 2 MB  512x2048 bf16
  u16*   y2b = (u16*)(ws + (4u << 20));    // 1 MB  512x1024 bf16
  float* pp  = (float*)(ws + (5u << 20));  // 16 KB 8x512 f32

  k_gather<<<BATCH, 256, 0, stream>>>(pairs, attrs, h_drug, xb);
  k_gemm<64><<<256, 256, 0, stream>>>(xb, W0, b0, y1b, N0, K0);
  k_gemm<32><<<256, 256, 0, stream>>>(y1b, W1, b1, y2b, N1, K0);
  k_head<<<256, 512, 0, stream>>>(cells, y2b, L0, O0, L1, pp);
  k_final<<<1, 512, 0, stream>>>(cells, pp, O1, out);
}